// Round 13
// baseline (510.796 us; speedup 1.0000x reference)
//
#include <hip/hip_runtime.h>
#include <cstdint>
#include <cstddef>

// ---------------------------------------------------------------------------
// GAT forward: N=30000, E=480000 (+N self loops), ATOM=HID=128, H=4, OUT=256
// Outputs: probs [64,2] then alpha2 [E+N, 4], flat in d_out.
// R2: CSR-by-destination + per-wave softmax/aggregate (no edge atomics).
// R7: sorted-batch count; lane-parallel alpha into per-wave LDS.
// R8: bf16 gather copy. R10: score dots in gemm epilogue; LN in gat_agg.
// R11: bf16 MFMA GEMM (16x16x32); merged MLP head.
// R12: pooling fused into gat_agg concat epilogue (out2 buffer + pool_k
//      dispatch removed; block-level LDS partial + atomics); gather unroll 2.
// ---------------------------------------------------------------------------

typedef __attribute__((ext_vector_type(8))) short bf16x8;
typedef __attribute__((ext_vector_type(4))) float f32x4;

__device__ __forceinline__ float lrelu(float v) { return v >= 0.f ? v : 0.2f * v; }

__device__ __forceinline__ float4 lrelu4(float4 v) {
    return make_float4(lrelu(v.x), lrelu(v.y), lrelu(v.z), lrelu(v.w));
}
__device__ __forceinline__ float4 add4(float4 a, float4 b) {
    return make_float4(a.x + b.x, a.y + b.y, a.z + b.z, a.w + b.w);
}

// round-to-nearest-even float -> bf16 bits
__device__ __forceinline__ unsigned short f2bf(float x) {
    unsigned int u = __float_as_uint(x);
    u += 0x7FFFu + ((u >> 16) & 1u);
    return (unsigned short)(u >> 16);
}

// ---------------------------------------------------------------------------
// fp32 -> bf16 elementwise (for x)
// ---------------------------------------------------------------------------
__global__ void cvt_bf16_k(const float* __restrict__ src,
                           unsigned short* __restrict__ dst, int n4) {
    int i = blockIdx.x * 256 + threadIdx.x;
    if (i >= n4) return;
    float4 v = *(const float4*)&src[i * 4];
    ushort4 o;
    o.x = f2bf(v.x); o.y = f2bf(v.y); o.z = f2bf(v.z); o.w = f2bf(v.w);
    *(ushort4*)&dst[i * 4] = o;
}

// W[128k][512] fp32 -> Wbt[head][128col][128k] bf16 (both layers, z picks W)
__global__ void cvt_wt_k(const float* __restrict__ W1, const float* __restrict__ W2,
                         unsigned short* __restrict__ Wt1, unsigned short* __restrict__ Wt2) {
    const float* W = blockIdx.z ? W2 : W1;
    unsigned short* Wt = blockIdx.z ? Wt2 : Wt1;
    int head = blockIdx.y;
    int idx = blockIdx.x * 256 + threadIdx.x;   // 16384 per head
    int k = idx >> 7, c = idx & 127;
    Wt[((size_t)head * 128 + c) * 128 + k] = f2bf(W[(size_t)k * 512 + head * 128 + c]);
}

// ---------------------------------------------------------------------------
// MFMA GEMM: hb[M,512](bf16) = Abf[M,128] @ W (via Wbt[head][col][k]).
// Block = 64 rows x 1 head (128 cols), 4 waves. Fused score dots (fp32 acc).
// ---------------------------------------------------------------------------
__global__ __launch_bounds__(256) void gemm_mfma(const unsigned short* __restrict__ Abf,
                                                 const unsigned short* __restrict__ Wbt,
                                                 unsigned short* __restrict__ hbout,
                                                 const float* __restrict__ a_s,
                                                 const float* __restrict__ a_d,
                                                 float* __restrict__ ssrc,
                                                 float* __restrict__ sdst, int M) {
    __shared__ unsigned short Als[64][136];
    __shared__ unsigned short Bls[128][136];
    const int tid = threadIdx.x;
    const int row0 = blockIdx.x * 64;
    const int head = blockIdx.y;

#pragma unroll
    for (int i = 0; i < 4; i++) {
        int c = tid + i * 256;
        int r = c >> 4, k0 = (c & 15) * 8;
        uint4 v = make_uint4(0, 0, 0, 0);
        int gr = row0 + r;
        if (gr < M) v = *(const uint4*)&Abf[(size_t)gr * 128 + k0];
        *(uint4*)&Als[r][k0] = v;
    }
    const unsigned short* Wh = Wbt + (size_t)head * 128 * 128;
#pragma unroll
    for (int i = 0; i < 8; i++) {
        int c = tid + i * 256;
        int col = c >> 4, k0 = (c & 15) * 8;
        *(uint4*)&Bls[col][k0] = *(const uint4*)&Wh[col * 128 + k0];
    }
    __syncthreads();

    const int w = tid >> 6, l = tid & 63;
    const int li = l & 15, lg = l >> 4;

    f32x4 acc[8] = {};
#pragma unroll
    for (int kt = 0; kt < 4; kt++) {
        bf16x8 a = *(const bf16x8*)&Als[w * 16 + li][kt * 32 + lg * 8];
#pragma unroll
        for (int ct = 0; ct < 8; ct++) {
            bf16x8 b = *(const bf16x8*)&Bls[ct * 16 + li][kt * 32 + lg * 8];
            acc[ct] = __builtin_amdgcn_mfma_f32_16x16x32_bf16(a, b, acc[ct], 0, 0, 0);
        }
    }

#pragma unroll
    for (int ct = 0; ct < 8; ct++) {
#pragma unroll
        for (int r = 0; r < 4; r++) {
            int gr = row0 + w * 16 + lg * 4 + r;
            if (gr < M)
                hbout[(size_t)gr * 512 + head * 128 + ct * 16 + li] = f2bf(acc[ct][r]);
        }
    }

    float ps[4] = {}, pd[4] = {};
#pragma unroll
    for (int ct = 0; ct < 8; ct++) {
        float as_v = a_s[head * 128 + ct * 16 + li];
        float ad_v = a_d[head * 128 + ct * 16 + li];
#pragma unroll
        for (int r = 0; r < 4; r++) { ps[r] += acc[ct][r] * as_v; pd[r] += acc[ct][r] * ad_v; }
    }
#pragma unroll
    for (int o = 1; o <= 8; o <<= 1) {
#pragma unroll
        for (int r = 0; r < 4; r++) { ps[r] += __shfl_xor(ps[r], o); pd[r] += __shfl_xor(pd[r], o); }
    }
    if (li == 0) {
#pragma unroll
        for (int r = 0; r < 4; r++) {
            int gr = row0 + w * 16 + lg * 4 + r;
            if (gr < M) { ssrc[gr * 4 + head] = ps[r]; sdst[gr * 4 + head] = pd[r]; }
        }
    }
}

// ---------------------------------------------------------------------------
// CSR build: histogram of dst -> prefix scan -> fill (csr_src, csr_eid).
// ---------------------------------------------------------------------------
__global__ void hist_k(const int* __restrict__ ei, int E, int ET, int* __restrict__ deg) {
    int e = blockIdx.x * 256 + threadIdx.x;
    if (e >= ET) return;
    int d = (e < E) ? ei[E + e] : e - E;
    atomicAdd(&deg[d], 1);
}

__global__ __launch_bounds__(1024) void scan_k(const int* __restrict__ deg,
                                               int* __restrict__ rowptr,
                                               int* __restrict__ cursor, int Nn) {
    __shared__ int part[1024];
    int t = threadIdx.x;
    int per = (Nn + 1023) / 1024;
    int b0 = t * per, b1 = min(b0 + per, Nn);
    int s = 0;
    for (int i = b0; i < b1; i++) s += deg[i];
    part[t] = s;
    __syncthreads();
    for (int o = 1; o < 1024; o <<= 1) {
        int x = (t >= o) ? part[t - o] : 0;
        __syncthreads();
        part[t] += x;
        __syncthreads();
    }
    int off = part[t] - s;
    for (int i = b0; i < b1; i++) {
        rowptr[i] = off; cursor[i] = off; off += deg[i];
    }
    if (t == 1023) rowptr[Nn] = part[1023];
}

__global__ void fill_csr_k(const int* __restrict__ ei, int E, int ET,
                           int* __restrict__ cursor,
                           int* __restrict__ csr_src, int* __restrict__ csr_eid) {
    int e = blockIdx.x * 256 + threadIdx.x;
    if (e >= ET) return;
    int s, d;
    if (e < E) { s = ei[e]; d = ei[E + e]; } else { s = d = e - E; }
    int pos = atomicAdd(&cursor[d], 1);
    csr_src[pos] = s;
    csr_eid[pos] = e;
}

// ---------------------------------------------------------------------------
// Fused per-destination softmax + aggregate. One wave per dst (4 dst/block).
// concat=0: head-mean + b1 + LN + lrelu -> outb[Nn,128] bf16.
// concat=1: alpha -> aout; pooled[g] += lrelu(acc + b2) fused (LDS partial
//           across the block's 4 waves when single-graph, else per-wave).
// ---------------------------------------------------------------------------
__global__ __launch_bounds__(256) void gat_agg(const int* __restrict__ rowptr,
                                               const int* __restrict__ csr_src,
                                               const int* __restrict__ csr_eid,
                                               const float4* __restrict__ ssrc,
                                               const float4* __restrict__ sdst,
                                               const unsigned short* __restrict__ hb,
                                               unsigned short* __restrict__ outb,
                                               float4* __restrict__ aout,
                                               const float* __restrict__ b1,
                                               const float* __restrict__ gln,
                                               const float* __restrict__ bln,
                                               const float* __restrict__ b2,
                                               const int* __restrict__ batch,
                                               float* __restrict__ pooled,
                                               int Nn, int concat) {
    __shared__ float alds[4][64][4];
    __shared__ float pp[512];
    __shared__ int gids[4];
    const int t = threadIdx.x;
    const int lane = t & 63;
    const int w = t >> 6;
    const int d = blockIdx.x * 4 + w;
    const bool active = d < Nn;

    if (concat) {
        pp[t] = 0.f; pp[t + 256] = 0.f;
        if (lane == 0) gids[w] = active ? batch[d] : -1;
    }
    __syncthreads();

    float acc[8] = {};
    if (active) {
        const int beg = rowptr[d], end = rowptr[d + 1];
        const float4 sd = sdst[d];
        const float NINF = -__builtin_huge_valf();

        float4 m = make_float4(NINF, NINF, NINF, NINF);
        for (int i = beg + lane; i < end; i += 64) {
            float4 ev = lrelu4(add4(ssrc[csr_src[i]], sd));
            m.x = fmaxf(m.x, ev.x); m.y = fmaxf(m.y, ev.y);
            m.z = fmaxf(m.z, ev.z); m.w = fmaxf(m.w, ev.w);
        }
        for (int o = 32; o; o >>= 1) {
            m.x = fmaxf(m.x, __shfl_xor(m.x, o));
            m.y = fmaxf(m.y, __shfl_xor(m.y, o));
            m.z = fmaxf(m.z, __shfl_xor(m.z, o));
            m.w = fmaxf(m.w, __shfl_xor(m.w, o));
        }

        float4 den = make_float4(0.f, 0.f, 0.f, 0.f);
        for (int i = beg + lane; i < end; i += 64) {
            float4 ev = lrelu4(add4(ssrc[csr_src[i]], sd));
            den.x += __expf(ev.x - m.x); den.y += __expf(ev.y - m.y);
            den.z += __expf(ev.z - m.z); den.w += __expf(ev.w - m.w);
        }
        for (int o = 32; o; o >>= 1) {
            den.x += __shfl_xor(den.x, o);
            den.y += __shfl_xor(den.y, o);
            den.z += __shfl_xor(den.z, o);
            den.w += __shfl_xor(den.w, o);
        }
        float4 inv;
        inv.x = 1.f / den.x; inv.y = 1.f / den.y;
        inv.z = 1.f / den.z; inv.w = 1.f / den.w;

        const int head = lane >> 4;
        for (int chunk = beg; chunk < end; chunk += 64) {
            const int n = min(64, end - chunk);
            if (lane < n) {
                int i = chunk + lane;
                float4 ev = lrelu4(add4(ssrc[csr_src[i]], sd));
                float4 a4;
                a4.x = __expf(ev.x - m.x) * inv.x;
                a4.y = __expf(ev.y - m.y) * inv.y;
                a4.z = __expf(ev.z - m.z) * inv.z;
                a4.w = __expf(ev.w - m.w) * inv.w;
                alds[w][lane][0] = a4.x; alds[w][lane][1] = a4.y;
                alds[w][lane][2] = a4.z; alds[w][lane][3] = a4.w;
                if (concat) aout[csr_eid[i]] = a4;
            }
#pragma unroll 2
            for (int j = 0; j < n; ++j) {
                int s = csr_src[chunk + j];
                float a = alds[w][j][head];
                uint4 q = *(const uint4*)(hb + (size_t)s * 512 + lane * 8);
                acc[0] += a * __uint_as_float(q.x << 16);
                acc[1] += a * __uint_as_float(q.x & 0xFFFF0000u);
                acc[2] += a * __uint_as_float(q.y << 16);
                acc[3] += a * __uint_as_float(q.y & 0xFFFF0000u);
                acc[4] += a * __uint_as_float(q.z << 16);
                acc[5] += a * __uint_as_float(q.z & 0xFFFF0000u);
                acc[6] += a * __uint_as_float(q.w << 16);
                acc[7] += a * __uint_as_float(q.w & 0xFFFF0000u);
            }
        }
    }

    if (concat) {
        // fused pooling: val = lrelu(acc + b2); sum per graph.
        const int c0 = lane * 8;
        float val[8];
        if (active) {
#pragma unroll
            for (int k = 0; k < 8; k++) val[k] = lrelu(acc[k] + b2[c0 + k]);
        }
        const bool uniform = (gids[0] >= 0) && (gids[0] == gids[3]);
        if (uniform && active) {
#pragma unroll
            for (int k = 0; k < 8; k++) atomicAdd(&pp[c0 + k], val[k]);
        }
        __syncthreads();
        if (uniform) {
            const int g0 = gids[0];
            atomicAdd(&pooled[g0 * 512 + t], pp[t]);
            atomicAdd(&pooled[g0 * 512 + t + 256], pp[t + 256]);
        } else if (active) {
            const int gw = gids[w];
#pragma unroll
            for (int k = 0; k < 8; k++) atomicAdd(&pooled[gw * 512 + c0 + k], val[k]);
        }
    } else if (active) {
        // head-mean across lane groups {l, l^16, l^32, l^48}
#pragma unroll
        for (int k = 0; k < 8; k++) acc[k] += __shfl_xor(acc[k], 16);
#pragma unroll
        for (int k = 0; k < 8; k++) acc[k] += __shfl_xor(acc[k], 32);
        // fused: x = mean + b1; LayerNorm(128); lrelu; write bf16
        const int c0 = (lane & 15) * 8;
        float val[8];
        float s = 0.f;
#pragma unroll
        for (int k = 0; k < 8; k++) { val[k] = 0.25f * acc[k] + b1[c0 + k]; s += val[k]; }
#pragma unroll
        for (int o = 1; o <= 8; o <<= 1) s += __shfl_xor(s, o);
        float mu = s * (1.f / 128.f);
        float v = 0.f;
#pragma unroll
        for (int k = 0; k < 8; k++) { float dk = val[k] - mu; v += dk * dk; }
#pragma unroll
        for (int o = 1; o <= 8; o <<= 1) v += __shfl_xor(v, o);
        float r = rsqrtf(v * (1.f / 128.f) + 1e-5f);
        if (lane < 16) {
            unsigned int u[4];
#pragma unroll
            for (int k = 0; k < 4; k++) {
                float y0 = lrelu(gln[c0 + 2 * k]     * (val[2 * k]     - mu) * r + bln[c0 + 2 * k]);
                float y1 = lrelu(gln[c0 + 2 * k + 1] * (val[2 * k + 1] - mu) * r + bln[c0 + 2 * k + 1]);
                u[k] = (unsigned int)f2bf(y0) | ((unsigned int)f2bf(y1) << 16);
            }
            *(uint4*)&outb[(size_t)d * 128 + c0] = make_uint4(u[0], u[1], u[2], u[3]);
        }
    }
}

// ---------------------------------------------------------------------------
// Whole MLP head in one kernel: one block per graph g (256 threads).
// ---------------------------------------------------------------------------
__device__ __forceinline__ float block_sum(float v, volatile float* sbuf, int tid, int nw) {
    for (int o = 32; o; o >>= 1) v += __shfl_down(v, o);
    if ((tid & 63) == 0) sbuf[tid >> 6] = v;
    __syncthreads();
    if (tid == 0) { float r = 0.f; for (int i = 0; i < nw; i++) r += sbuf[i]; sbuf[0] = r; }
    __syncthreads();
    float r = sbuf[0];
    __syncthreads();
    return r;
}

__global__ __launch_bounds__(256) void mlp_head(const float* __restrict__ pooled,
                                                const int* __restrict__ batch, int Nn,
                                                const float* __restrict__ Wl0, const float* __restrict__ bl0,
                                                const float* __restrict__ Ws1, const float* __restrict__ bs1,
                                                const float* __restrict__ g1,  const float* __restrict__ bb1,
                                                const float* __restrict__ Ws2, const float* __restrict__ bs2,
                                                const float* __restrict__ g2,  const float* __restrict__ bb2,
                                                const float* __restrict__ Ws3, const float* __restrict__ bs3,
                                                float* __restrict__ probs) {
    __shared__ float z0[128], z1[256], z2[128];
    __shared__ float sbuf[8];
    const int g = blockIdx.x, t = threadIdx.x;

    int lo = 0, hi = Nn;
    while (lo < hi) { int mid = (lo + hi) >> 1; if (batch[mid] < g) lo = mid + 1; else hi = mid; }
    int a = lo;
    lo = 0; hi = Nn;
    while (lo < hi) { int mid = (lo + hi) >> 1; if (batch[mid] < g + 1) lo = mid + 1; else hi = mid; }
    float inv = 1.f / fmaxf((float)(lo - a), 1.f);

    if (t < 128) {
        float acc = 0.f;
        for (int k = 0; k < 512; k++) acc += pooled[g * 512 + k] * Wl0[k * 128 + t];
        z0[t] = acc * inv + bl0[t];
    }
    __syncthreads();

    {
        float acc = bs1[t];
        for (int k = 0; k < 128; k++) acc += z0[k] * Ws1[k * 256 + t];
        float mu = block_sum(acc, sbuf, t, 4) * (1.f / 256.f);
        float dd = acc - mu;
        float var = block_sum(dd * dd, sbuf, t, 4) * (1.f / 256.f);
        z1[t] = fmaxf(g1[t] * dd * rsqrtf(var + 1e-5f) + bb1[t], 0.f);
    }
    __syncthreads();

    {
        float acc = 0.f;
        if (t < 128) {
            acc = bs2[t];
            for (int k = 0; k < 256; k++) acc += z1[k] * Ws2[k * 128 + t];
        }
        float mu = block_sum(acc, sbuf, t, 4) * (1.f / 128.f);
        float dd = (t < 128) ? acc - mu : 0.f;
        float var = block_sum(dd * dd, sbuf, t, 4) * (1.f / 128.f);
        if (t < 128) z2[t] = fmaxf(g2[t] * dd * rsqrtf(var + 1e-5f) + bb2[t], 0.f);
    }
    __syncthreads();

    if (t == 0) {
        float p0 = bs3[0], p1 = bs3[1];
        for (int k = 0; k < 128; k++) { p0 += z2[k] * Ws3[k * 2]; p1 += z2[k] * Ws3[k * 2 + 1]; }
        float mx = fmaxf(p0, p1);
        float e0 = __expf(p0 - mx), e1 = __expf(p1 - mx);
        float s = e0 + e1;
        probs[g * 2 + 0] = e0 / s;
        probs[g * 2 + 1] = e1 / s;
    }
}

// ---------------------------------------------------------------------------
extern "C" void kernel_launch(void* const* d_in, const int* in_sizes, int n_in,
                              void* d_out, int out_size, void* d_ws, size_t ws_size,
                              hipStream_t stream) {
    const float* x    = (const float*)d_in[0];
    const int*   ei   = (const int*)d_in[1];
    const int*   batch= (const int*)d_in[2];
    const float* W1   = (const float*)d_in[3];
    const float* as1  = (const float*)d_in[4];
    const float* ad1  = (const float*)d_in[5];
    const float* b1   = (const float*)d_in[6];
    const float* g_ln = (const float*)d_in[7];
    const float* b_ln = (const float*)d_in[8];
    const float* W2   = (const float*)d_in[9];
    const float* as2  = (const float*)d_in[10];
    const float* ad2  = (const float*)d_in[11];
    const float* b2   = (const float*)d_in[12];
    const float* Wl0  = (const float*)d_in[13];
    const float* bl0  = (const float*)d_in[14];
    const float* Ws1  = (const float*)d_in[15];
    const float* bs1  = (const float*)d_in[16];
    const float* g1   = (const float*)d_in[17];
    const float* bb1  = (const float*)d_in[18];
    const float* Ws2  = (const float*)d_in[19];
    const float* bs2  = (const float*)d_in[20];
    const float* g2   = (const float*)d_in[21];
    const float* bb2  = (const float*)d_in[22];
    const float* Ws3  = (const float*)d_in[23];
    const float* bs3  = (const float*)d_in[24];
    (void)n_in; (void)out_size; (void)ws_size;

    const int Nn = in_sizes[0] / 128;   // 30000
    const int E  = in_sizes[1] / 2;     // 480000
    const int ET = E + Nn;              // 510000
    const int G  = 64;

    // ---- workspace layout ----
    char* ws = (char*)d_ws;
    size_t off = 0;
    auto alloc = [&](size_t bytes) { void* p = ws + off; off += (bytes + 255) & ~(size_t)255; return p; };
    unsigned short* hb   = (unsigned short*)alloc((size_t)Nn * 512 * 2); // bf16 h
    unsigned short* xb   = (unsigned short*)alloc((size_t)Nn * 128 * 2); // bf16 x
    unsigned short* hlnb = (unsigned short*)alloc((size_t)Nn * 128 * 2); // bf16 LN(out1)
    unsigned short* Wbt1 = (unsigned short*)alloc((size_t)4 * 128 * 128 * 2);
    unsigned short* Wbt2 = (unsigned short*)alloc((size_t)4 * 128 * 128 * 2);
    float* pooled = (float*)alloc((size_t)G * 512 * 4);
    float* ssrc   = (float*)alloc((size_t)Nn * 4 * 4);
    float* sdst   = (float*)alloc((size_t)Nn * 4 * 4);
    int*   deg    = (int*)alloc((size_t)Nn * 4);
    int*   rowptr = (int*)alloc((size_t)(Nn + 1) * 4);
    int*   cursor = (int*)alloc((size_t)Nn * 4);
    int*   csr_src= (int*)alloc((size_t)ET * 4);
    int*   csr_eid= (int*)alloc((size_t)ET * 4);

    float* probs = (float*)d_out;
    float* aout  = (float*)d_out + 128;   // alpha [ET,4]

    // ---- init ----
    hipMemsetAsync(deg, 0, (size_t)Nn * 4, stream);
    hipMemsetAsync(pooled, 0, (size_t)G * 512 * 4, stream);

    const int eblks = (ET + 255) / 256;
    dim3 ggrid((Nn + 63) / 64, 4);
    const int ablks = (Nn + 3) / 4;

    // ---- input conversions ----
    cvt_bf16_k<<<(Nn * 128 / 4 + 255) / 256, 256, 0, stream>>>(x, xb, Nn * 128 / 4);
    cvt_wt_k<<<dim3(64, 4, 2), 256, 0, stream>>>(W1, W2, Wbt1, Wbt2);

    // ---- CSR build ----
    hist_k<<<eblks, 256, 0, stream>>>(ei, E, ET, deg);
    scan_k<<<1, 1024, 0, stream>>>(deg, rowptr, cursor, Nn);
    fill_csr_k<<<eblks, 256, 0, stream>>>(ei, E, ET, cursor, csr_src, csr_eid);

    // ---- layer 1 ----
    gemm_mfma<<<ggrid, 256, 0, stream>>>(xb, Wbt1, hb, as1, ad1, ssrc, sdst, Nn);
    gat_agg<<<ablks, 256, 0, stream>>>(rowptr, csr_src, csr_eid,
                                       (const float4*)ssrc, (const float4*)sdst,
                                       hb, hlnb, nullptr, b1, g_ln, b_ln,
                                       nullptr, nullptr, nullptr, Nn, 0);

    // ---- layer 2 (pooling fused) ----
    gemm_mfma<<<ggrid, 256, 0, stream>>>(hlnb, Wbt2, hb, as2, ad2, ssrc, sdst, Nn);
    gat_agg<<<ablks, 256, 0, stream>>>(rowptr, csr_src, csr_eid,
                                       (const float4*)ssrc, (const float4*)sdst,
                                       hb, nullptr, (float4*)aout, nullptr, nullptr, nullptr,
                                       b2, batch, pooled, Nn, 1);

    // ---- MLP head ----
    mlp_head<<<G, 256, 0, stream>>>(pooled, batch, Nn, Wl0, bl0, Ws1, bs1, g1, bb1,
                                    Ws2, bs2, g2, bb2, Ws3, bs3, probs);
}

// Round 15
// 473.329 us; speedup vs baseline: 1.0792x; 1.0792x over previous
//
#include <hip/hip_runtime.h>
#include <cstdint>
#include <cstddef>

// ---------------------------------------------------------------------------
// GAT forward: N=30000, E=480000 (+N self loops), ATOM=HID=128, H=4, OUT=256
// Outputs: probs [64,2] then alpha2 [E+N, 4], flat in d_out.
// R2: CSR-by-destination + per-wave softmax/aggregate. R7: sorted count;
// lane-parallel alpha. R8: bf16 gather copy. R10: score dots in gemm
// epilogue; LN in gat_agg. R11: bf16 MFMA GEMM; merged MLP head (484us).
// R12 REGRESSION (511us): pooling fusion restructured the gather loop
// (VGPR 44->32, BW 3.7->2.1 TB/s). R13: full revert of gat_agg to R11
// structure; single delta = layer-2 output stored bf16 (halves out2 write
// + pool_k read); float4 pooled reads in mlp_head.
// R14: identical resubmit (R14 bench was an acquisition timeout).
// ---------------------------------------------------------------------------

typedef __attribute__((ext_vector_type(8))) short bf16x8;
typedef __attribute__((ext_vector_type(4))) float f32x4;

__device__ __forceinline__ float lrelu(float v) { return v >= 0.f ? v : 0.2f * v; }

__device__ __forceinline__ float4 lrelu4(float4 v) {
    return make_float4(lrelu(v.x), lrelu(v.y), lrelu(v.z), lrelu(v.w));
}
__device__ __forceinline__ float4 add4(float4 a, float4 b) {
    return make_float4(a.x + b.x, a.y + b.y, a.z + b.z, a.w + b.w);
}

// round-to-nearest-even float -> bf16 bits
__device__ __forceinline__ unsigned short f2bf(float x) {
    unsigned int u = __float_as_uint(x);
    u += 0x7FFFu + ((u >> 16) & 1u);
    return (unsigned short)(u >> 16);
}
__device__ __forceinline__ float bf2f(unsigned short b) {
    return __uint_as_float(((unsigned int)b) << 16);
}

// ---------------------------------------------------------------------------
// fp32 -> bf16 elementwise (for x)
// ---------------------------------------------------------------------------
__global__ void cvt_bf16_k(const float* __restrict__ src,
                           unsigned short* __restrict__ dst, int n4) {
    int i = blockIdx.x * 256 + threadIdx.x;
    if (i >= n4) return;
    float4 v = *(const float4*)&src[i * 4];
    ushort4 o;
    o.x = f2bf(v.x); o.y = f2bf(v.y); o.z = f2bf(v.z); o.w = f2bf(v.w);
    *(ushort4*)&dst[i * 4] = o;
}

// W[128k][512] fp32 -> Wbt[head][128col][128k] bf16 (both layers, z picks W)
__global__ void cvt_wt_k(const float* __restrict__ W1, const float* __restrict__ W2,
                         unsigned short* __restrict__ Wt1, unsigned short* __restrict__ Wt2) {
    const float* W = blockIdx.z ? W2 : W1;
    unsigned short* Wt = blockIdx.z ? Wt2 : Wt1;
    int head = blockIdx.y;
    int idx = blockIdx.x * 256 + threadIdx.x;   // 16384 per head
    int k = idx >> 7, c = idx & 127;
    Wt[((size_t)head * 128 + c) * 128 + k] = f2bf(W[(size_t)k * 512 + head * 128 + c]);
}

// ---------------------------------------------------------------------------
// MFMA GEMM: hb[M,512](bf16) = Abf[M,128] @ W (via Wbt[head][col][k]).
// Block = 64 rows x 1 head (128 cols), 4 waves. Fused score dots (fp32 acc).
// ---------------------------------------------------------------------------
__global__ __launch_bounds__(256) void gemm_mfma(const unsigned short* __restrict__ Abf,
                                                 const unsigned short* __restrict__ Wbt,
                                                 unsigned short* __restrict__ hbout,
                                                 const float* __restrict__ a_s,
                                                 const float* __restrict__ a_d,
                                                 float* __restrict__ ssrc,
                                                 float* __restrict__ sdst, int M) {
    __shared__ unsigned short Als[64][136];
    __shared__ unsigned short Bls[128][136];
    const int tid = threadIdx.x;
    const int row0 = blockIdx.x * 64;
    const int head = blockIdx.y;

#pragma unroll
    for (int i = 0; i < 4; i++) {
        int c = tid + i * 256;
        int r = c >> 4, k0 = (c & 15) * 8;
        uint4 v = make_uint4(0, 0, 0, 0);
        int gr = row0 + r;
        if (gr < M) v = *(const uint4*)&Abf[(size_t)gr * 128 + k0];
        *(uint4*)&Als[r][k0] = v;
    }
    const unsigned short* Wh = Wbt + (size_t)head * 128 * 128;
#pragma unroll
    for (int i = 0; i < 8; i++) {
        int c = tid + i * 256;
        int col = c >> 4, k0 = (c & 15) * 8;
        *(uint4*)&Bls[col][k0] = *(const uint4*)&Wh[col * 128 + k0];
    }
    __syncthreads();

    const int w = tid >> 6, l = tid & 63;
    const int li = l & 15, lg = l >> 4;

    f32x4 acc[8] = {};
#pragma unroll
    for (int kt = 0; kt < 4; kt++) {
        bf16x8 a = *(const bf16x8*)&Als[w * 16 + li][kt * 32 + lg * 8];
#pragma unroll
        for (int ct = 0; ct < 8; ct++) {
            bf16x8 b = *(const bf16x8*)&Bls[ct * 16 + li][kt * 32 + lg * 8];
            acc[ct] = __builtin_amdgcn_mfma_f32_16x16x32_bf16(a, b, acc[ct], 0, 0, 0);
        }
    }

#pragma unroll
    for (int ct = 0; ct < 8; ct++) {
#pragma unroll
        for (int r = 0; r < 4; r++) {
            int gr = row0 + w * 16 + lg * 4 + r;
            if (gr < M)
                hbout[(size_t)gr * 512 + head * 128 + ct * 16 + li] = f2bf(acc[ct][r]);
        }
    }

    float ps[4] = {}, pd[4] = {};
#pragma unroll
    for (int ct = 0; ct < 8; ct++) {
        float as_v = a_s[head * 128 + ct * 16 + li];
        float ad_v = a_d[head * 128 + ct * 16 + li];
#pragma unroll
        for (int r = 0; r < 4; r++) { ps[r] += acc[ct][r] * as_v; pd[r] += acc[ct][r] * ad_v; }
    }
#pragma unroll
    for (int o = 1; o <= 8; o <<= 1) {
#pragma unroll
        for (int r = 0; r < 4; r++) { ps[r] += __shfl_xor(ps[r], o); pd[r] += __shfl_xor(pd[r], o); }
    }
    if (li == 0) {
#pragma unroll
        for (int r = 0; r < 4; r++) {
            int gr = row0 + w * 16 + lg * 4 + r;
            if (gr < M) { ssrc[gr * 4 + head] = ps[r]; sdst[gr * 4 + head] = pd[r]; }
        }
    }
}

// ---------------------------------------------------------------------------
// CSR build: histogram of dst -> prefix scan -> fill (csr_src, csr_eid).
// ---------------------------------------------------------------------------
__global__ void hist_k(const int* __restrict__ ei, int E, int ET, int* __restrict__ deg) {
    int e = blockIdx.x * 256 + threadIdx.x;
    if (e >= ET) return;
    int d = (e < E) ? ei[E + e] : e - E;
    atomicAdd(&deg[d], 1);
}

__global__ __launch_bounds__(1024) void scan_k(const int* __restrict__ deg,
                                               int* __restrict__ rowptr,
                                               int* __restrict__ cursor, int Nn) {
    __shared__ int part[1024];
    int t = threadIdx.x;
    int per = (Nn + 1023) / 1024;
    int b0 = t * per, b1 = min(b0 + per, Nn);
    int s = 0;
    for (int i = b0; i < b1; i++) s += deg[i];
    part[t] = s;
    __syncthreads();
    for (int o = 1; o < 1024; o <<= 1) {
        int x = (t >= o) ? part[t - o] : 0;
        __syncthreads();
        part[t] += x;
        __syncthreads();
    }
    int off = part[t] - s;
    for (int i = b0; i < b1; i++) {
        rowptr[i] = off; cursor[i] = off; off += deg[i];
    }
    if (t == 1023) rowptr[Nn] = part[1023];
}

__global__ void fill_csr_k(const int* __restrict__ ei, int E, int ET,
                           int* __restrict__ cursor,
                           int* __restrict__ csr_src, int* __restrict__ csr_eid) {
    int e = blockIdx.x * 256 + threadIdx.x;
    if (e >= ET) return;
    int s, d;
    if (e < E) { s = ei[e]; d = ei[E + e]; } else { s = d = e - E; }
    int pos = atomicAdd(&cursor[d], 1);
    csr_src[pos] = s;
    csr_eid[pos] = e;
}

// ---------------------------------------------------------------------------
// Fused per-destination softmax + aggregate. One wave per dst (4 dst/block).
// Gathers bf16 hb. concat=0: head-mean + b1 + LN + lrelu -> outb[Nn,128] bf16.
// concat=1: outb[Nn,512] bf16 (+alpha to aout).  [R11 structure exactly]
// ---------------------------------------------------------------------------
__global__ __launch_bounds__(256) void gat_agg(const int* __restrict__ rowptr,
                                               const int* __restrict__ csr_src,
                                               const int* __restrict__ csr_eid,
                                               const float4* __restrict__ ssrc,
                                               const float4* __restrict__ sdst,
                                               const unsigned short* __restrict__ hb,
                                               unsigned short* __restrict__ outb,
                                               float4* __restrict__ aout,
                                               const float* __restrict__ b1,
                                               const float* __restrict__ gln,
                                               const float* __restrict__ bln,
                                               int Nn, int concat) {
    __shared__ float alds[4][64][4];
    const int lane = threadIdx.x & 63;
    const int w = threadIdx.x >> 6;
    const int d = blockIdx.x * 4 + w;
    if (d >= Nn) return;
    const int beg = rowptr[d], end = rowptr[d + 1];
    const float4 sd = sdst[d];
    const float NINF = -__builtin_huge_valf();

    float4 m = make_float4(NINF, NINF, NINF, NINF);
    for (int i = beg + lane; i < end; i += 64) {
        float4 ev = lrelu4(add4(ssrc[csr_src[i]], sd));
        m.x = fmaxf(m.x, ev.x); m.y = fmaxf(m.y, ev.y);
        m.z = fmaxf(m.z, ev.z); m.w = fmaxf(m.w, ev.w);
    }
    for (int o = 32; o; o >>= 1) {
        m.x = fmaxf(m.x, __shfl_xor(m.x, o));
        m.y = fmaxf(m.y, __shfl_xor(m.y, o));
        m.z = fmaxf(m.z, __shfl_xor(m.z, o));
        m.w = fmaxf(m.w, __shfl_xor(m.w, o));
    }

    float4 den = make_float4(0.f, 0.f, 0.f, 0.f);
    for (int i = beg + lane; i < end; i += 64) {
        float4 ev = lrelu4(add4(ssrc[csr_src[i]], sd));
        den.x += __expf(ev.x - m.x); den.y += __expf(ev.y - m.y);
        den.z += __expf(ev.z - m.z); den.w += __expf(ev.w - m.w);
    }
    for (int o = 32; o; o >>= 1) {
        den.x += __shfl_xor(den.x, o);
        den.y += __shfl_xor(den.y, o);
        den.z += __shfl_xor(den.z, o);
        den.w += __shfl_xor(den.w, o);
    }
    float4 inv;
    inv.x = 1.f / den.x; inv.y = 1.f / den.y;
    inv.z = 1.f / den.z; inv.w = 1.f / den.w;

    const int head = lane >> 4;
    float acc[8] = {};
    for (int chunk = beg; chunk < end; chunk += 64) {
        const int n = min(64, end - chunk);
        if (lane < n) {
            int i = chunk + lane;
            float4 ev = lrelu4(add4(ssrc[csr_src[i]], sd));
            float4 a4;
            a4.x = __expf(ev.x - m.x) * inv.x;
            a4.y = __expf(ev.y - m.y) * inv.y;
            a4.z = __expf(ev.z - m.z) * inv.z;
            a4.w = __expf(ev.w - m.w) * inv.w;
            alds[w][lane][0] = a4.x; alds[w][lane][1] = a4.y;
            alds[w][lane][2] = a4.z; alds[w][lane][3] = a4.w;
            if (aout != nullptr) aout[csr_eid[i]] = a4;
        }
        for (int j = 0; j < n; ++j) {
            int s = csr_src[chunk + j];
            float a = alds[w][j][head];
            uint4 q = *(const uint4*)(hb + (size_t)s * 512 + lane * 8);
            acc[0] += a * __uint_as_float(q.x << 16);
            acc[1] += a * __uint_as_float(q.x & 0xFFFF0000u);
            acc[2] += a * __uint_as_float(q.y << 16);
            acc[3] += a * __uint_as_float(q.y & 0xFFFF0000u);
            acc[4] += a * __uint_as_float(q.z << 16);
            acc[5] += a * __uint_as_float(q.z & 0xFFFF0000u);
            acc[6] += a * __uint_as_float(q.w << 16);
            acc[7] += a * __uint_as_float(q.w & 0xFFFF0000u);
        }
    }

    if (concat) {
        // write bf16 out2 row (8 ch/lane = 16B, lanes consecutive -> 1KB/wave)
        unsigned int u[4];
#pragma unroll
        for (int k = 0; k < 4; k++)
            u[k] = (unsigned int)f2bf(acc[2 * k]) | ((unsigned int)f2bf(acc[2 * k + 1]) << 16);
        *(uint4*)&outb[(size_t)d * 512 + lane * 8] = make_uint4(u[0], u[1], u[2], u[3]);
    } else {
        // head-mean across lane groups {l, l^16, l^32, l^48}
#pragma unroll
        for (int k = 0; k < 8; k++) acc[k] += __shfl_xor(acc[k], 16);
#pragma unroll
        for (int k = 0; k < 8; k++) acc[k] += __shfl_xor(acc[k], 32);
        // fused: x = mean + b1; LayerNorm(128); lrelu; write bf16
        const int c0 = (lane & 15) * 8;
        float val[8];
        float s = 0.f;
#pragma unroll
        for (int k = 0; k < 8; k++) { val[k] = 0.25f * acc[k] + b1[c0 + k]; s += val[k]; }
#pragma unroll
        for (int o = 1; o <= 8; o <<= 1) s += __shfl_xor(s, o);
        float mu = s * (1.f / 128.f);
        float v = 0.f;
#pragma unroll
        for (int k = 0; k < 8; k++) { float dk = val[k] - mu; v += dk * dk; }
#pragma unroll
        for (int o = 1; o <= 8; o <<= 1) v += __shfl_xor(v, o);
        float r = rsqrtf(v * (1.f / 128.f) + 1e-5f);
        if (lane < 16) {
            unsigned int u[4];
#pragma unroll
            for (int k = 0; k < 4; k++) {
                float y0 = lrelu(gln[c0 + 2 * k]     * (val[2 * k]     - mu) * r + bln[c0 + 2 * k]);
                float y1 = lrelu(gln[c0 + 2 * k + 1] * (val[2 * k + 1] - mu) * r + bln[c0 + 2 * k + 1]);
                u[k] = (unsigned int)f2bf(y0) | ((unsigned int)f2bf(y1) << 16);
            }
            *(uint4*)&outb[(size_t)d * 128 + c0] = make_uint4(u[0], u[1], u[2], u[3]);
        }
    }
}

// pooled[g,c] += sum over nodes of lrelu(bf16(out2[n,c])+b2[c]); batch sorted.
__global__ __launch_bounds__(512) void pool_k(const unsigned short* __restrict__ out2b,
                                              const float* __restrict__ b2,
                                              const int* __restrict__ batch,
                                              float* __restrict__ pooled, int Nn) {
    int c = threadIdx.x;
    int n0 = blockIdx.x * 64, n1 = min(n0 + 64, Nn);
    if (n0 >= Nn) return;
    float bc = b2[c];
    int g = batch[n0];
    float acc = 0.f;
    for (int n = n0; n < n1; ++n) {
        int bg = batch[n];
        if (bg != g) { atomicAdd(&pooled[g * 512 + c], acc); acc = 0.f; g = bg; }
        float v = bf2f(out2b[(size_t)n * 512 + c]) + bc;
        acc += lrelu(v);
    }
    atomicAdd(&pooled[g * 512 + c], acc);
}

// ---------------------------------------------------------------------------
// Whole MLP head in one kernel: one block per graph g (256 threads).
// ---------------------------------------------------------------------------
__device__ __forceinline__ float block_sum(float v, volatile float* sbuf, int tid, int nw) {
    for (int o = 32; o; o >>= 1) v += __shfl_down(v, o);
    if ((tid & 63) == 0) sbuf[tid >> 6] = v;
    __syncthreads();
    if (tid == 0) { float r = 0.f; for (int i = 0; i < nw; i++) r += sbuf[i]; sbuf[0] = r; }
    __syncthreads();
    float r = sbuf[0];
    __syncthreads();
    return r;
}

__global__ __launch_bounds__(256) void mlp_head(const float* __restrict__ pooled,
                                                const int* __restrict__ batch, int Nn,
                                                const float* __restrict__ Wl0, const float* __restrict__ bl0,
                                                const float* __restrict__ Ws1, const float* __restrict__ bs1,
                                                const float* __restrict__ g1,  const float* __restrict__ bb1,
                                                const float* __restrict__ Ws2, const float* __restrict__ bs2,
                                                const float* __restrict__ g2,  const float* __restrict__ bb2,
                                                const float* __restrict__ Ws3, const float* __restrict__ bs3,
                                                float* __restrict__ probs) {
    __shared__ float z0[128], z1[256], z2[128];
    __shared__ float sbuf[8];
    const int g = blockIdx.x, t = threadIdx.x;

    int lo = 0, hi = Nn;
    while (lo < hi) { int mid = (lo + hi) >> 1; if (batch[mid] < g) lo = mid + 1; else hi = mid; }
    int a = lo;
    lo = 0; hi = Nn;
    while (lo < hi) { int mid = (lo + hi) >> 1; if (batch[mid] < g + 1) lo = mid + 1; else hi = mid; }
    float inv = 1.f / fmaxf((float)(lo - a), 1.f);

    if (t < 128) {
        float acc = 0.f;
        for (int k = 0; k < 512; k += 4) {
            float4 p = *(const float4*)&pooled[g * 512 + k];
            acc += p.x * Wl0[k * 128 + t]       + p.y * Wl0[(k + 1) * 128 + t]
                 + p.z * Wl0[(k + 2) * 128 + t] + p.w * Wl0[(k + 3) * 128 + t];
        }
        z0[t] = acc * inv + bl0[t];
    }
    __syncthreads();

    {
        float acc = bs1[t];
        for (int k = 0; k < 128; k++) acc += z0[k] * Ws1[k * 256 + t];
        float mu = block_sum(acc, sbuf, t, 4) * (1.f / 256.f);
        float dd = acc - mu;
        float var = block_sum(dd * dd, sbuf, t, 4) * (1.f / 256.f);
        z1[t] = fmaxf(g1[t] * dd * rsqrtf(var + 1e-5f) + bb1[t], 0.f);
    }
    __syncthreads();

    {
        float acc = 0.f;
        if (t < 128) {
            acc = bs2[t];
            for (int k = 0; k < 256; k++) acc += z1[k] * Ws2[k * 128 + t];
        }
        float mu = block_sum(acc, sbuf, t, 4) * (1.f / 128.f);
        float dd = (t < 128) ? acc - mu : 0.f;
        float var = block_sum(dd * dd, sbuf, t, 4) * (1.f / 128.f);
        if (t < 128) z2[t] = fmaxf(g2[t] * dd * rsqrtf(var + 1e-5f) + bb2[t], 0.f);
    }
    __syncthreads();

    if (t == 0) {
        float p0 = bs3[0], p1 = bs3[1];
        for (int k = 0; k < 128; k++) { p0 += z2[k] * Ws3[k * 2]; p1 += z2[k] * Ws3[k * 2 + 1]; }
        float mx = fmaxf(p0, p1);
        float e0 = __expf(p0 - mx), e1 = __expf(p1 - mx);
        float s = e0 + e1;
        probs[g * 2 + 0] = e0 / s;
        probs[g * 2 + 1] = e1 / s;
    }
}

// ---------------------------------------------------------------------------
extern "C" void kernel_launch(void* const* d_in, const int* in_sizes, int n_in,
                              void* d_out, int out_size, void* d_ws, size_t ws_size,
                              hipStream_t stream) {
    const float* x    = (const float*)d_in[0];
    const int*   ei   = (const int*)d_in[1];
    const int*   batch= (const int*)d_in[2];
    const float* W1   = (const float*)d_in[3];
    const float* as1  = (const float*)d_in[4];
    const float* ad1  = (const float*)d_in[5];
    const float* b1   = (const float*)d_in[6];
    const float* g_ln = (const float*)d_in[7];
    const float* b_ln = (const float*)d_in[8];
    const float* W2   = (const float*)d_in[9];
    const float* as2  = (const float*)d_in[10];
    const float* ad2  = (const float*)d_in[11];
    const float* b2   = (const float*)d_in[12];
    const float* Wl0  = (const float*)d_in[13];
    const float* bl0  = (const float*)d_in[14];
    const float* Ws1  = (const float*)d_in[15];
    const float* bs1  = (const float*)d_in[16];
    const float* g1   = (const float*)d_in[17];
    const float* bb1  = (const float*)d_in[18];
    const float* Ws2  = (const float*)d_in[19];
    const float* bs2  = (const float*)d_in[20];
    const float* g2   = (const float*)d_in[21];
    const float* bb2  = (const float*)d_in[22];
    const float* Ws3  = (const float*)d_in[23];
    const float* bs3  = (const float*)d_in[24];
    (void)n_in; (void)out_size; (void)ws_size;

    const int Nn = in_sizes[0] / 128;   // 30000
    const int E  = in_sizes[1] / 2;     // 480000
    const int ET = E + Nn;              // 510000
    const int G  = 64;

    // ---- workspace layout ----
    char* ws = (char*)d_ws;
    size_t off = 0;
    auto alloc = [&](size_t bytes) { void* p = ws + off; off += (bytes + 255) & ~(size_t)255; return p; };
    unsigned short* hb   = (unsigned short*)alloc((size_t)Nn * 512 * 2); // bf16 h
    unsigned short* xb   = (unsigned short*)alloc((size_t)Nn * 128 * 2); // bf16 x
    unsigned short* hlnb = (unsigned short*)alloc((size_t)Nn * 128 * 2); // bf16 LN(out1)
    unsigned short* out2b= (unsigned short*)alloc((size_t)Nn * 512 * 2); // bf16 out2
    unsigned short* Wbt1 = (unsigned short*)alloc((size_t)4 * 128 * 128 * 2);
    unsigned short* Wbt2 = (unsigned short*)alloc((size_t)4 * 128 * 128 * 2);
    float* pooled = (float*)alloc((size_t)G * 512 * 4);
    float* ssrc   = (float*)alloc((size_t)Nn * 4 * 4);
    float* sdst   = (float*)alloc((size_t)Nn * 4 * 4);
    int*   deg    = (int*)alloc((size_t)Nn * 4);
    int*   rowptr = (int*)alloc((size_t)(Nn + 1) * 4);
    int*   cursor = (int*)alloc((size_t)Nn * 4);
    int*   csr_src= (int*)alloc((size_t)ET * 4);
    int*   csr_eid= (int*)alloc((size_t)ET * 4);

    float* probs = (float*)d_out;
    float* aout  = (float*)d_out + 128;   // alpha [ET,4]

    // ---- init ----
    hipMemsetAsync(deg, 0, (size_t)Nn * 4, stream);
    hipMemsetAsync(pooled, 0, (size_t)G * 512 * 4, stream);

    const int eblks = (ET + 255) / 256;
    dim3 ggrid((Nn + 63) / 64, 4);
    const int ablks = (Nn + 3) / 4;

    // ---- input conversions ----
    cvt_bf16_k<<<(Nn * 128 / 4 + 255) / 256, 256, 0, stream>>>(x, xb, Nn * 128 / 4);
    cvt_wt_k<<<dim3(64, 4, 2), 256, 0, stream>>>(W1, W2, Wbt1, Wbt2);

    // ---- CSR build ----
    hist_k<<<eblks, 256, 0, stream>>>(ei, E, ET, deg);
    scan_k<<<1, 1024, 0, stream>>>(deg, rowptr, cursor, Nn);
    fill_csr_k<<<eblks, 256, 0, stream>>>(ei, E, ET, cursor, csr_src, csr_eid);

    // ---- layer 1 ----
    gemm_mfma<<<ggrid, 256, 0, stream>>>(xb, Wbt1, hb, as1, ad1, ssrc, sdst, Nn);
    gat_agg<<<ablks, 256, 0, stream>>>(rowptr, csr_src, csr_eid,
                                       (const float4*)ssrc, (const float4*)sdst,
                                       hb, hlnb, nullptr, b1, g_ln, b_ln, Nn, 0);

    // ---- layer 2 ----
    gemm_mfma<<<ggrid, 256, 0, stream>>>(hlnb, Wbt2, hb, as2, ad2, ssrc, sdst, Nn);
    gat_agg<<<ablks, 256, 0, stream>>>(rowptr, csr_src, csr_eid,
                                       (const float4*)ssrc, (const float4*)sdst,
                                       hb, out2b, (float4*)aout,
                                       nullptr, nullptr, nullptr, Nn, 1);

    // ---- pool + MLP head ----
    pool_k<<<(Nn + 63) / 64, 512, 0, stream>>>(out2b, b2, batch, pooled, Nn);
    mlp_head<<<G, 256, 0, stream>>>(pooled, batch, Nn, Wl0, bl0, Ws1, bs1, g1, bb1,
                                    Ws2, bs2, g2, bb2, Ws3, bs3, probs);
}